// Round 11
// baseline (1479.542 us; speedup 1.0000x reference)
//
#include <hip/hip_runtime.h>

#define SWEEPS 8
#define HSTRIDE 4112   // hTbuf row stride: 4096 + front pad(1) + slack, %4==0
#define WL 168         // w-LDS row width: 128 + skew(12) + k-rotation(28)

__device__ __forceinline__ float sig_(float x) { return 1.0f / (1.0f + __expf(-x)); }
__device__ __forceinline__ float th_(float x)  { return 1.0f - 2.0f / (__expf(2.0f * x) + 1.0f); }

// ---------------------------------------------------------------------------
// emb2 build: emb2[v][j] = sum_k emb[v][k]*tWih[j][k] + tb[j]   (j = 0..1023)
// grid (32, 16), block 256, tile 64v x 64j, 4x4 microtile. 512 blocks.
// ---------------------------------------------------------------------------
__global__ __launch_bounds__(256, 2)
void gemm_emb2(const float* __restrict__ A, const float* __restrict__ Wt,
               const float* __restrict__ bias, float* __restrict__ Cout, int M)
{
    __shared__ float a_lds[32][68];
    __shared__ float b_lds[32][68];
    const int tid = threadIdx.x;
    const int tn = tid & 15;
    const int th = tid >> 4;
    const int m0 = blockIdx.x * 64;
    const int j0 = blockIdx.y * 64;

    float acc[4][4];
    #pragma unroll
    for (int x = 0; x < 4; ++x)
        #pragma unroll
        for (int y = 0; y < 4; ++y) acc[x][y] = 0.f;

    float4 abuf[2], bbuf[2];
    auto load_t = [&](int k0) {
        #pragma unroll
        for (int p = 0; p < 2; ++p) {
            int idx = tid + p * 256, ml = idx >> 3, k4 = idx & 7;
            int row = m0 + ml;
            abuf[p] = (row < M) ? *(const float4*)&A[row * 256 + k0 + k4 * 4]
                                : make_float4(0.f, 0.f, 0.f, 0.f);
            bbuf[p] = *(const float4*)&Wt[(j0 + ml) * 256 + k0 + k4 * 4];
        }
    };
    auto store_t = [&]() {
        #pragma unroll
        for (int p = 0; p < 2; ++p) {
            int idx = tid + p * 256, ml = idx >> 3, k4 = idx & 7;
            a_lds[k4 * 4 + 0][ml] = abuf[p].x;
            a_lds[k4 * 4 + 1][ml] = abuf[p].y;
            a_lds[k4 * 4 + 2][ml] = abuf[p].z;
            a_lds[k4 * 4 + 3][ml] = abuf[p].w;
            b_lds[k4 * 4 + 0][ml] = bbuf[p].x;
            b_lds[k4 * 4 + 1][ml] = bbuf[p].y;
            b_lds[k4 * 4 + 2][ml] = bbuf[p].z;
            b_lds[k4 * 4 + 3][ml] = bbuf[p].w;
        }
    };

    load_t(0); store_t(); __syncthreads();
    for (int c = 0; c < 8; ++c) {
        if (c < 7) load_t((c + 1) * 32);
        #pragma unroll 8
        for (int k = 0; k < 32; ++k) {
            float4 a4 = *(const float4*)&a_lds[k][tn * 4];
            float4 b4 = *(const float4*)&b_lds[k][th * 4];
            float av[4] = {a4.x, a4.y, a4.z, a4.w};
            float bv[4] = {b4.x, b4.y, b4.z, b4.w};
            #pragma unroll
            for (int mi = 0; mi < 4; ++mi)
                #pragma unroll
                for (int ji = 0; ji < 4; ++ji)
                    acc[mi][ji] += av[mi] * bv[ji];
        }
        __syncthreads();
        if (c < 7) { store_t(); __syncthreads(); }
    }

    const int jcol = j0 + th * 4;
    float4 bs = *(const float4*)&bias[jcol];
    #pragma unroll
    for (int mi = 0; mi < 4; ++mi) {
        int row = m0 + tn * 4 + mi;
        if (row < M) {
            float4 o;
            o.x = acc[mi][0] + bs.x;
            o.y = acc[mi][1] + bs.y;
            o.z = acc[mi][2] + bs.z;
            o.w = acc[mi][3] + bs.w;
            *(float4*)&Cout[row * 1024 + jcol] = o;
        }
    }
}

// ---------------------------------------------------------------------------
// Counting sort of sequences by length, DESCENDING. One block.
// perm[p] = original n of sorted slot p; actcnt[t] = #{n : len[n] > t}.
// ---------------------------------------------------------------------------
__global__ __launch_bounds__(256)
void sortlen(const int* __restrict__ len, int* __restrict__ perm,
             int* __restrict__ actcnt)
{
    __shared__ int cnt[17], off[17];
    const int tid = threadIdx.x;
    if (tid < 17) cnt[tid] = 0;
    __syncthreads();
    for (int n = tid; n < 4096; n += 256) atomicAdd(&cnt[len[n]], 1);
    __syncthreads();
    if (tid == 0) {
        int run = 0;
        for (int L = 16; L >= 1; --L) { off[L] = run; run += cnt[L]; }
        actcnt[16] = 0;
        for (int t = 1; t < 16; ++t) actcnt[t] = off[t];
        actcnt[0] = 4096;
    }
    __syncthreads();
    for (int n = tid; n < 4096; n += 256) {
        int pos = atomicAdd(&off[len[n]], 1);
        perm[pos] = n;
    }
}

// ---------------------------------------------------------------------------
// Token-LSTM step 0 (h0=c0=0 -> pointwise emb2 gather), TRANSPOSED + sorted.
// ---------------------------------------------------------------------------
__global__ __launch_bounds__(256)
void step0T(const int* __restrict__ tok, const int* __restrict__ perm,
            const int* __restrict__ actcnt, const float* __restrict__ emb2,
            float* __restrict__ cT, float* __restrict__ hT0,
            float* __restrict__ featsT)
{
    const int tid = threadIdx.x;
    const int tn = tid & 15, tu = tid >> 4;
    const int u  = blockIdx.y * 16 + tu;
    const int n0 = blockIdx.x * 64 + tn * 4;
    const int a1 = actcnt[1];
    int4 pn = *(const int4*)&perm[n0];
    const int pns[4] = {pn.x, pn.y, pn.z, pn.w};
    float h4[4], c4[4];
    #pragma unroll
    for (int j = 0; j < 4; ++j) {
        int v = tok[pns[j] * 16];
        const float* e = emb2 + v * 1024 + u;
        float ig = e[0], gg = e[512], og = e[768];
        float c = sig_(ig) * th_(gg);
        float h = sig_(og) * th_(c);
        c4[j] = c; h4[j] = h;
        if (n0 + j >= a1) featsT[u * 4096 + pns[j]] = h;   // len == 1
    }
    *(float4*)&cT[u * 4096 + n0]  = make_float4(c4[0], c4[1], c4[2], c4[3]);
    *(float4*)&hT0[u * 4096 + n0] = make_float4(h4[0], h4[1], h4[2], h4[3]);
}

// ---------------------------------------------------------------------------
// Token-LSTM step t (t>=1), fused, TRANSPOSED, sorted, 128r x 64s (8x4).
// grid (64, 8) = 512 blocks = 2/CU (the round-9 sweet spot).
// w-LDS store col = rl + 4*(rl>>5) + 4*k4: transpose writes exactly 2-way
// (validated in r10: conflicts 5.4e6 -> 2e6); reads get uniform +4*(k>>2)
// offset, stay 2-way broadcast. Double-buffered chunks, 1 barrier/chunk.
// Early-exit on actcnt (length-sorted slots).
// ---------------------------------------------------------------------------
__global__ __launch_bounds__(256, 2)
void stepT(const float* __restrict__ Whh, const float* __restrict__ hTprev,
           const int* __restrict__ tok, int t, const float* __restrict__ emb2,
           const int* __restrict__ perm, const int* __restrict__ actcnt,
           float* __restrict__ cT, float* __restrict__ hTnext,
           float* __restrict__ featsT)
{
    const int s0 = blockIdx.x * 64;
    const int a_t  = actcnt[t];
    if (s0 >= a_t) return;                // inactive tile: all lengths <= t
    const int a_t1 = actcnt[t + 1];

    __shared__ float w_lds[2][32][WL];    // [buf][k][col(rl,k4)]
    __shared__ float h_lds[2][32][68];    // [buf][k][s]
    const int tid = threadIdx.x;
    const int tr = tid & 15;              // r-octet
    const int ts = tid >> 4;              // s-quad
    const int ub = blockIdx.y;            // unit-tile (32 units)
    const int scol = s0 + ts * 4;
    const int wbase = tr * 8 + ((tr >> 2) << 2);

    // prefetch epilogue inputs early (independent of GEMM)
    int4 pn = *(const int4*)&perm[scol];
    const int pns[4] = {pn.x, pn.y, pn.z, pn.w};
    int vids[4];
    #pragma unroll
    for (int j = 0; j < 4; ++j) vids[j] = tok[pns[j] * 16 + t];

    float acc[8][4];
    #pragma unroll
    for (int x = 0; x < 8; ++x)
        #pragma unroll
        for (int y = 0; y < 4; ++y) acc[x][y] = 0.f;

    float4 wbuf[4], hbuf[2];
    auto load_t = [&](int k0) {
        #pragma unroll
        for (int p = 0; p < 4; ++p) {
            int idx = tid + p * 256;
            int rl = idx >> 3, k4 = idx & 7;
            int gi = rl & 3, ii = rl >> 2;
            wbuf[p] = *(const float4*)&Whh[(gi * 256 + ub * 32 + ii) * 256 + k0 + k4 * 4];
        }
        #pragma unroll
        for (int p = 0; p < 2; ++p) {
            int idx = tid + p * 256;
            int jj = idx >> 4, s4 = idx & 15;
            hbuf[p] = *(const float4*)&hTprev[(k0 + jj) * 4096 + s0 + s4 * 4];
        }
    };
    auto store_t = [&](int b) {
        #pragma unroll
        for (int p = 0; p < 4; ++p) {
            int idx = tid + p * 256;
            int rl = idx >> 3, k4 = idx & 7;
            int pc = rl + ((rl >> 5) << 2) + (k4 << 2);
            w_lds[b][k4 * 4 + 0][pc] = wbuf[p].x;
            w_lds[b][k4 * 4 + 1][pc] = wbuf[p].y;
            w_lds[b][k4 * 4 + 2][pc] = wbuf[p].z;
            w_lds[b][k4 * 4 + 3][pc] = wbuf[p].w;
        }
        #pragma unroll
        for (int p = 0; p < 2; ++p) {
            int idx = tid + p * 256;
            int jj = idx >> 4, s4 = idx & 15;
            *(float4*)&h_lds[b][jj][s4 * 4] = hbuf[p];
        }
    };

    load_t(0); store_t(0); __syncthreads();
    for (int c = 0; c < 8; ++c) {
        const int b = c & 1;
        if (c < 7) load_t((c + 1) * 32);
        #pragma unroll 8
        for (int k = 0; k < 32; ++k) {
            const int rot = (k >> 2) << 2;
            float4 w0 = *(const float4*)&w_lds[b][k][wbase + rot];
            float4 w1 = *(const float4*)&w_lds[b][k][wbase + rot + 4];
            float4 hv = *(const float4*)&h_lds[b][k][ts * 4];
            float wa[8] = {w0.x, w0.y, w0.z, w0.w, w1.x, w1.y, w1.z, w1.w};
            float ha[4] = {hv.x, hv.y, hv.z, hv.w};
            #pragma unroll
            for (int ri = 0; ri < 8; ++ri)
                #pragma unroll
                for (int si = 0; si < 4; ++si)
                    acc[ri][si] += wa[ri] * ha[si];
        }
        if (c < 7) store_t(b ^ 1);        // other buffer: no WAR hazard
        __syncthreads();                  // one barrier per chunk
    }

    // epilogue: 2 units x 4 slots LSTM update
    #pragma unroll
    for (int half = 0; half < 2; ++half) {
        const int u = ub * 32 + tr * 2 + half;
        float4 cold = *(const float4*)&cT[u * 4096 + scol];
        const float* coldp = (const float*)&cold;
        float c4[4], h4[4];
        #pragma unroll
        for (int j = 0; j < 4; ++j) {
            const float* e = emb2 + vids[j] * 1024 + u;
            float ig = acc[half * 4 + 0][j] + e[0];
            float fg = acc[half * 4 + 1][j] + e[256];
            float gg = acc[half * 4 + 2][j] + e[512];
            float og = acc[half * 4 + 3][j] + e[768];
            float cc = sig_(fg) * coldp[j] + sig_(ig) * th_(gg);
            c4[j] = cc;
            h4[j] = sig_(og) * th_(cc);
            int p = scol + j;
            if (p >= a_t1 && p < a_t)      // len == t+1: last valid step
                featsT[u * 4096 + pns[j]] = h4[j];
        }
        *(float4*)&cT[u * 4096 + scol]     = make_float4(c4[0], c4[1], c4[2], c4[3]);
        *(float4*)&hTnext[u * 4096 + scol] = make_float4(h4[0], h4[1], h4[2], h4[3]);
    }
}

// ---------------------------------------------------------------------------
// T-GEMM 128r x 64s (8x4): Out[r][s] = sum_k W[r][k]*X[k*xstride+s] + add.
// Same skew/rotation as stepT. grid (64, 8), 2 blocks/CU.
// Phase-2: X = hTbuf (HSTRIDE, front pad -> X[k][s] = h[k][s-1]).
// ---------------------------------------------------------------------------
__global__ __launch_bounds__(256, 2)
void gemm_T(const float* __restrict__ W, const float* __restrict__ X, int xstride,
            const float* __restrict__ addm, const float* __restrict__ bias,
            float* __restrict__ Out)
{
    __shared__ float w_lds[2][32][WL];
    __shared__ float h_lds[2][32][68];
    const int tid = threadIdx.x;
    const int tr = tid & 15;
    const int ts = tid >> 4;
    const int s0 = blockIdx.x * 64;
    const int r0 = blockIdx.y * 128;
    const int wbase = tr * 8 + ((tr >> 2) << 2);

    float acc[8][4];
    #pragma unroll
    for (int x = 0; x < 8; ++x)
        #pragma unroll
        for (int y = 0; y < 4; ++y) acc[x][y] = 0.f;

    float4 wbuf[4], hbuf[2];
    auto load_t = [&](int k0) {
        #pragma unroll
        for (int p = 0; p < 4; ++p) {
            int idx = tid + p * 256;
            int r = idx >> 3, k4 = idx & 7;
            wbuf[p] = *(const float4*)&W[(r0 + r) * 256 + k0 + k4 * 4];
        }
        #pragma unroll
        for (int p = 0; p < 2; ++p) {
            int idx = tid + p * 256;
            int jj = idx >> 4, s4 = idx & 15;
            hbuf[p] = *(const float4*)&X[(k0 + jj) * xstride + s0 + s4 * 4];
        }
    };
    auto store_t = [&](int b) {
        #pragma unroll
        for (int p = 0; p < 4; ++p) {
            int idx = tid + p * 256;
            int rl = idx >> 3, k4 = idx & 7;
            int pc = rl + ((rl >> 5) << 2) + (k4 << 2);
            w_lds[b][k4 * 4 + 0][pc] = wbuf[p].x;
            w_lds[b][k4 * 4 + 1][pc] = wbuf[p].y;
            w_lds[b][k4 * 4 + 2][pc] = wbuf[p].z;
            w_lds[b][k4 * 4 + 3][pc] = wbuf[p].w;
        }
        #pragma unroll
        for (int p = 0; p < 2; ++p) {
            int idx = tid + p * 256;
            int jj = idx >> 4, s4 = idx & 15;
            *(float4*)&h_lds[b][jj][s4 * 4] = hbuf[p];
        }
    };

    load_t(0); store_t(0); __syncthreads();
    for (int c = 0; c < 8; ++c) {
        const int b = c & 1;
        if (c < 7) load_t((c + 1) * 32);
        #pragma unroll 8
        for (int k = 0; k < 32; ++k) {
            const int rot = (k >> 2) << 2;
            float4 w0 = *(const float4*)&w_lds[b][k][wbase + rot];
            float4 w1 = *(const float4*)&w_lds[b][k][wbase + rot + 4];
            float4 hv = *(const float4*)&h_lds[b][k][ts * 4];
            float wa[8] = {w0.x, w0.y, w0.z, w0.w, w1.x, w1.y, w1.z, w1.w};
            float ha[4] = {hv.x, hv.y, hv.z, hv.w};
            #pragma unroll
            for (int ri = 0; ri < 8; ++ri)
                #pragma unroll
                for (int si = 0; si < 4; ++si)
                    acc[ri][si] += wa[ri] * ha[si];
        }
        if (c < 7) store_t(b ^ 1);
        __syncthreads();
    }

    const int scol = s0 + ts * 4;
    #pragma unroll
    for (int ri = 0; ri < 8; ++ri) {
        const int r = r0 + tr * 8 + ri;
        float4 z;
        if (addm) {
            float4 gb = *(const float4*)&addm[r * 4096 + scol];
            z.x = acc[ri][0] + gb.x; z.y = acc[ri][1] + gb.y;
            z.z = acc[ri][2] + gb.z; z.w = acc[ri][3] + gb.w;
        } else {
            float bb = bias[r];
            z.x = acc[ri][0] + bb; z.y = acc[ri][1] + bb;
            z.z = acc[ri][2] + bb; z.w = acc[ri][3] + bb;
        }
        *(float4*)&Out[r * 4096 + scol] = z;
    }
}

// ---------------------------------------------------------------------------
// Sweep scan: exact per-unit affine scan of c given gate preactivations ZT,
// then h = sig(o)*tanh(c) -> hTbuf[u][1+s]. grid 256, block 256.
// ---------------------------------------------------------------------------
__global__ __launch_bounds__(256, 1)
void scan_sweep(const float* __restrict__ ZT, float* __restrict__ hTbuf)
{
    const int u = blockIdx.x;
    const int t = threadIdx.x;
    const int s0 = t * 16;

    const float* zi = ZT + (0 * 256 + u) * 4096 + s0;
    const float* zf = ZT + (1 * 256 + u) * 4096 + s0;
    const float* zg = ZT + (2 * 256 + u) * 4096 + s0;
    const float* zo = ZT + (3 * 256 + u) * 4096 + s0;

    float4 iv[4], fv[4], gv[4], ov[4];
    #pragma unroll
    for (int p = 0; p < 4; ++p) {
        iv[p] = *(const float4*)&zi[p * 4];
        fv[p] = *(const float4*)&zf[p * 4];
        gv[p] = *(const float4*)&zg[p * 4];
        ov[p] = *(const float4*)&zo[p * 4];
    }
    float af[16], uu[16];
    const float* ivp = (const float*)iv;
    const float* fvp = (const float*)fv;
    const float* gvp = (const float*)gv;
    float A = 1.f, U = 0.f;
    #pragma unroll
    for (int k = 0; k < 16; ++k) {
        af[k] = sig_(fvp[k]);
        uu[k] = sig_(ivp[k]) * th_(gvp[k]);
        U = af[k] * U + uu[k];
        A = af[k] * A;
    }

    __shared__ float As[256], Us[256];
    As[t] = A; Us[t] = U;
    __syncthreads();
    #pragma unroll
    for (int off = 1; off < 256; off <<= 1) {
        float eA = 1.f, eU = 0.f;
        if (t >= off) { eA = As[t - off]; eU = Us[t - off]; }
        __syncthreads();
        U = A * eU + U;
        A = A * eA;
        As[t] = A; Us[t] = U;
        __syncthreads();
    }
    float c = (t > 0) ? Us[t - 1] : 0.f;  // exclusive prefix -> entry c

    float* hp = hTbuf + u * HSTRIDE + 1 + s0;
    const float* ovp = (const float*)ov;
    #pragma unroll
    for (int k = 0; k < 16; ++k) {
        c = af[k] * c + uu[k];
        hp[k] = sig_(ovp[k]) * th_(c);
    }
}

// ---------------------------------------------------------------------------
// Final linear: out = h[4095] . lin_W + lin_b
// ---------------------------------------------------------------------------
__global__ __launch_bounds__(256)
void out_kernel(const float* __restrict__ hTbuf, const float* __restrict__ linW,
                const float* __restrict__ linb, float* __restrict__ out)
{
    const int tid = threadIdx.x;
    __shared__ float red_lds[4];
    float p = hTbuf[tid * HSTRIDE + 4096] * linW[tid];
    #pragma unroll
    for (int off = 1; off < 64; off <<= 1) p += __shfl_xor(p, off);
    if ((tid & 63) == 0) red_lds[tid >> 6] = p;
    __syncthreads();
    if (tid == 0)
        out[0] = red_lds[0] + red_lds[1] + red_lds[2] + red_lds[3] + linb[0];
}

extern "C" void kernel_launch(void* const* d_in, const int* in_sizes, int n_in,
                              void* d_out, int out_size, void* d_ws, size_t ws_size,
                              hipStream_t stream)
{
    const int*   tok  = (const int*)d_in[0];
    const int*   len  = (const int*)d_in[1];
    const float* emb  = (const float*)d_in[2];
    const float* tWih = (const float*)d_in[3];
    const float* tWhh = (const float*)d_in[4];
    const float* tb   = (const float*)d_in[5];
    const float* iWih = (const float*)d_in[6];
    const float* iWhh = (const float*)d_in[7];
    const float* ib   = (const float*)d_in[8];
    const float* lW   = (const float*)d_in[9];
    const float* lb   = (const float*)d_in[10];
    float* out = (float*)d_out;

    // workspace (floats), ~44 MB; ZT (phase 2) aliases hT0..featsT (dead)
    float* emb2   = (float*)d_ws;           // [2000][1024]   8 MB
    float* hT0    = emb2   + 2048000;       // [256][4096]    4 MB
    float* hT1    = hT0    + 1048576;       // [256][4096]
    float* cT     = hT1    + 1048576;       // [256][4096]
    float* featsT = cT     + 1048576;       // [256][4096]
    float* gBT    = featsT + 1048576;       // [1024][4096]  16 MB
    float* hTbuf  = gBT    + 4194304;       // [256][HSTRIDE], col0 = 0 pad
    int*   perm   = (int*)(hTbuf + 256 * HSTRIDE);  // [4096]
    int*   actcnt = perm + 4096;            // [17]
    float* ZT     = hT0;                    // [1024][4096] alias (phase 2 only)

    // hTbuf col 0 must be 0 (h[-1])
    hipMemsetAsync(hTbuf, 0, (size_t)256 * HSTRIDE * sizeof(float), stream);

    // ---- phase 1: token LSTM, transposed, length-sorted batch-parallel ----
    sortlen<<<1, 256, 0, stream>>>(len, perm, actcnt);
    gemm_emb2<<<dim3(32, 16), 256, 0, stream>>>(emb, tWih, tb, emb2, 2000);
    step0T<<<dim3(64, 16), 256, 0, stream>>>(tok, perm, actcnt, emb2, cT, hT0,
                                             featsT);
    for (int t = 1; t < 16; ++t) {
        float* hprev = (t & 1) ? hT0 : hT1;
        float* hcur  = (t & 1) ? hT1 : hT0;
        stepT<<<dim3(64, 8), 256, 0, stream>>>(tWhh, hprev, tok, t, emb2, perm,
                                               actcnt, cT, hcur, featsT);
    }
    // gBT[r][s] = ins_W_ih . featsT + ins_b
    gemm_T<<<dim3(64, 8), 256, 0, stream>>>(iWih, featsT, 4096, nullptr, ib, gBT);

    // ---- phase 2: fixed-point sweeps (no cross-block sync) ----
    scan_sweep<<<256, 256, 0, stream>>>(gBT, hTbuf);    // sweep 1: h_old = 0
    for (int k = 1; k < SWEEPS; ++k) {
        gemm_T<<<dim3(64, 8), 256, 0, stream>>>(iWhh, hTbuf, HSTRIDE, gBT,
                                                nullptr, ZT);
        scan_sweep<<<256, 256, 0, stream>>>(ZT, hTbuf);
    }

    out_kernel<<<1, 256, 0, stream>>>(hTbuf, lW, lb, out);
}

// Round 12
// 1015.644 us; speedup vs baseline: 1.4568x; 1.4568x over previous
//
#include <hip/hip_runtime.h>

#define SWEEPS 8
#define HSTRIDE 4112   // hTbuf row stride: 4096 + front pad(1) + slack, %4==0

__device__ __forceinline__ float sig_(float x) { return 1.0f / (1.0f + __expf(-x)); }
__device__ __forceinline__ float th_(float x)  { return 1.0f - 2.0f / (__expf(2.0f * x) + 1.0f); }

// ---------------------------------------------------------------------------
// emb2 build: emb2[v][j] = sum_k emb[v][k]*tWih[j][k] + tb[j]   (j = 0..1023)
// grid (32, 16), block 256, tile 64v x 64j, 4x4 microtile. 512 blocks.
// ---------------------------------------------------------------------------
__global__ __launch_bounds__(256, 2)
void gemm_emb2(const float* __restrict__ A, const float* __restrict__ Wt,
               const float* __restrict__ bias, float* __restrict__ Cout, int M)
{
    __shared__ float a_lds[32][68];
    __shared__ float b_lds[32][68];
    const int tid = threadIdx.x;
    const int tn = tid & 15;
    const int th = tid >> 4;
    const int m0 = blockIdx.x * 64;
    const int j0 = blockIdx.y * 64;

    float acc[4][4];
    #pragma unroll
    for (int x = 0; x < 4; ++x)
        #pragma unroll
        for (int y = 0; y < 4; ++y) acc[x][y] = 0.f;

    float4 abuf[2], bbuf[2];
    auto load_t = [&](int k0) {
        #pragma unroll
        for (int p = 0; p < 2; ++p) {
            int idx = tid + p * 256, ml = idx >> 3, k4 = idx & 7;
            int row = m0 + ml;
            abuf[p] = (row < M) ? *(const float4*)&A[row * 256 + k0 + k4 * 4]
                                : make_float4(0.f, 0.f, 0.f, 0.f);
            bbuf[p] = *(const float4*)&Wt[(j0 + ml) * 256 + k0 + k4 * 4];
        }
    };
    auto store_t = [&]() {
        #pragma unroll
        for (int p = 0; p < 2; ++p) {
            int idx = tid + p * 256, ml = idx >> 3, k4 = idx & 7;
            a_lds[k4 * 4 + 0][ml] = abuf[p].x;
            a_lds[k4 * 4 + 1][ml] = abuf[p].y;
            a_lds[k4 * 4 + 2][ml] = abuf[p].z;
            a_lds[k4 * 4 + 3][ml] = abuf[p].w;
            b_lds[k4 * 4 + 0][ml] = bbuf[p].x;
            b_lds[k4 * 4 + 1][ml] = bbuf[p].y;
            b_lds[k4 * 4 + 2][ml] = bbuf[p].z;
            b_lds[k4 * 4 + 3][ml] = bbuf[p].w;
        }
    };

    load_t(0); store_t(); __syncthreads();
    for (int c = 0; c < 8; ++c) {
        if (c < 7) load_t((c + 1) * 32);
        #pragma unroll 8
        for (int k = 0; k < 32; ++k) {
            float4 a4 = *(const float4*)&a_lds[k][tn * 4];
            float4 b4 = *(const float4*)&b_lds[k][th * 4];
            float av[4] = {a4.x, a4.y, a4.z, a4.w};
            float bv[4] = {b4.x, b4.y, b4.z, b4.w};
            #pragma unroll
            for (int mi = 0; mi < 4; ++mi)
                #pragma unroll
                for (int ji = 0; ji < 4; ++ji)
                    acc[mi][ji] += av[mi] * bv[ji];
        }
        __syncthreads();
        if (c < 7) { store_t(); __syncthreads(); }
    }

    const int jcol = j0 + th * 4;
    float4 bs = *(const float4*)&bias[jcol];
    #pragma unroll
    for (int mi = 0; mi < 4; ++mi) {
        int row = m0 + tn * 4 + mi;
        if (row < M) {
            float4 o;
            o.x = acc[mi][0] + bs.x;
            o.y = acc[mi][1] + bs.y;
            o.z = acc[mi][2] + bs.z;
            o.w = acc[mi][3] + bs.w;
            *(float4*)&Cout[row * 1024 + jcol] = o;
        }
    }
}

// ---------------------------------------------------------------------------
// Counting sort of sequences by length, DESCENDING. One block.
// perm[p] = original n of sorted slot p; actcnt[t] = #{n : len[n] > t}.
// ---------------------------------------------------------------------------
__global__ __launch_bounds__(256)
void sortlen(const int* __restrict__ len, int* __restrict__ perm,
             int* __restrict__ actcnt)
{
    __shared__ int cnt[17], off[17];
    const int tid = threadIdx.x;
    if (tid < 17) cnt[tid] = 0;
    __syncthreads();
    for (int n = tid; n < 4096; n += 256) atomicAdd(&cnt[len[n]], 1);
    __syncthreads();
    if (tid == 0) {
        int run = 0;
        for (int L = 16; L >= 1; --L) { off[L] = run; run += cnt[L]; }
        actcnt[16] = 0;
        for (int t = 1; t < 16; ++t) actcnt[t] = off[t];
        actcnt[0] = 4096;
    }
    __syncthreads();
    for (int n = tid; n < 4096; n += 256) {
        int pos = atomicAdd(&off[len[n]], 1);
        perm[pos] = n;
    }
}

// ---------------------------------------------------------------------------
// Token-LSTM step 0 (h0=c0=0 -> pointwise emb2 gather), TRANSPOSED + sorted.
// ---------------------------------------------------------------------------
__global__ __launch_bounds__(256)
void step0T(const int* __restrict__ tok, const int* __restrict__ perm,
            const int* __restrict__ actcnt, const float* __restrict__ emb2,
            float* __restrict__ cT, float* __restrict__ hT0,
            float* __restrict__ featsT)
{
    const int tid = threadIdx.x;
    const int tn = tid & 15, tu = tid >> 4;
    const int u  = blockIdx.y * 16 + tu;
    const int n0 = blockIdx.x * 64 + tn * 4;
    const int a1 = actcnt[1];
    int4 pn = *(const int4*)&perm[n0];
    const int pns[4] = {pn.x, pn.y, pn.z, pn.w};
    float h4[4], c4[4];
    #pragma unroll
    for (int j = 0; j < 4; ++j) {
        int v = tok[pns[j] * 16];
        const float* e = emb2 + v * 1024 + u;
        float ig = e[0], gg = e[512], og = e[768];
        float c = sig_(ig) * th_(gg);
        float h = sig_(og) * th_(c);
        c4[j] = c; h4[j] = h;
        if (n0 + j >= a1) featsT[u * 4096 + pns[j]] = h;   // len == 1
    }
    *(float4*)&cT[u * 4096 + n0]  = make_float4(c4[0], c4[1], c4[2], c4[3]);
    *(float4*)&hT0[u * 4096 + n0] = make_float4(h4[0], h4[1], h4[2], h4[3]);
}

// ---------------------------------------------------------------------------
// Token-LSTM step t (t>=1), fused, TRANSPOSED, sorted, 128r x 64s (8x4).
// Early-exit: blocks with s0 >= actcnt[t] return (length-sorted slots).
// w-LDS skew: phys col = rl + 4*(rl>>5). Double-buffered chunks, one
// barrier per chunk. (Round-9 configuration — best measured: 44.5 us.)
// ---------------------------------------------------------------------------
__global__ __launch_bounds__(256, 2)
void stepT(const float* __restrict__ Whh, const float* __restrict__ hTprev,
           const int* __restrict__ tok, int t, const float* __restrict__ emb2,
           const int* __restrict__ perm, const int* __restrict__ actcnt,
           float* __restrict__ cT, float* __restrict__ hTnext,
           float* __restrict__ featsT)
{
    const int s0 = blockIdx.x * 64;
    const int a_t  = actcnt[t];
    if (s0 >= a_t) return;                // inactive tile: all lengths <= t
    const int a_t1 = actcnt[t + 1];

    __shared__ float w_lds[2][32][140];   // [buf][k][phys(rl)], skewed
    __shared__ float h_lds[2][32][68];    // [buf][k][s]
    const int tid = threadIdx.x;
    const int tr = tid & 15;              // r-octet
    const int ts = tid >> 4;              // s-quad
    const int ub = blockIdx.y;            // unit-tile (32 units)
    const int scol = s0 + ts * 4;
    const int wphys = tr * 8 + ((tr >> 2) << 2);

    // prefetch epilogue inputs early (independent of GEMM)
    int4 pn = *(const int4*)&perm[scol];
    const int pns[4] = {pn.x, pn.y, pn.z, pn.w};
    int vids[4];
    #pragma unroll
    for (int j = 0; j < 4; ++j) vids[j] = tok[pns[j] * 16 + t];

    float acc[8][4];
    #pragma unroll
    for (int x = 0; x < 8; ++x)
        #pragma unroll
        for (int y = 0; y < 4; ++y) acc[x][y] = 0.f;

    float4 wbuf[4], hbuf[2];
    auto load_t = [&](int k0) {
        #pragma unroll
        for (int p = 0; p < 4; ++p) {
            int idx = tid + p * 256;
            int rl = idx >> 3, k4 = idx & 7;
            int gi = rl & 3, ii = rl >> 2;
            wbuf[p] = *(const float4*)&Whh[(gi * 256 + ub * 32 + ii) * 256 + k0 + k4 * 4];
        }
        #pragma unroll
        for (int p = 0; p < 2; ++p) {
            int idx = tid + p * 256;
            int jj = idx >> 4, s4 = idx & 15;
            hbuf[p] = *(const float4*)&hTprev[(k0 + jj) * 4096 + s0 + s4 * 4];
        }
    };
    auto store_t = [&](int b) {
        #pragma unroll
        for (int p = 0; p < 4; ++p) {
            int idx = tid + p * 256;
            int rl = idx >> 3, k4 = idx & 7;
            int pc = rl + ((rl >> 5) << 2);
            w_lds[b][k4 * 4 + 0][pc] = wbuf[p].x;
            w_lds[b][k4 * 4 + 1][pc] = wbuf[p].y;
            w_lds[b][k4 * 4 + 2][pc] = wbuf[p].z;
            w_lds[b][k4 * 4 + 3][pc] = wbuf[p].w;
        }
        #pragma unroll
        for (int p = 0; p < 2; ++p) {
            int idx = tid + p * 256;
            int jj = idx >> 4, s4 = idx & 15;
            *(float4*)&h_lds[b][jj][s4 * 4] = hbuf[p];
        }
    };

    load_t(0); store_t(0); __syncthreads();
    for (int c = 0; c < 8; ++c) {
        const int b = c & 1;
        if (c < 7) load_t((c + 1) * 32);
        #pragma unroll 4
        for (int k = 0; k < 32; ++k) {
            float4 w0 = *(const float4*)&w_lds[b][k][wphys];
            float4 w1 = *(const float4*)&w_lds[b][k][wphys + 4];
            float4 hv = *(const float4*)&h_lds[b][k][ts * 4];
            float wa[8] = {w0.x, w0.y, w0.z, w0.w, w1.x, w1.y, w1.z, w1.w};
            float ha[4] = {hv.x, hv.y, hv.z, hv.w};
            #pragma unroll
            for (int ri = 0; ri < 8; ++ri)
                #pragma unroll
                for (int si = 0; si < 4; ++si)
                    acc[ri][si] += wa[ri] * ha[si];
        }
        if (c < 7) store_t(b ^ 1);        // other buffer: no WAR hazard
        __syncthreads();                  // one barrier per chunk
    }

    // epilogue: 2 units x 4 slots LSTM update
    #pragma unroll
    for (int half = 0; half < 2; ++half) {
        const int u = ub * 32 + tr * 2 + half;
        float4 cold = *(const float4*)&cT[u * 4096 + scol];
        const float* coldp = (const float*)&cold;
        float c4[4], h4[4];
        #pragma unroll
        for (int j = 0; j < 4; ++j) {
            const float* e = emb2 + vids[j] * 1024 + u;
            float ig = acc[half * 4 + 0][j] + e[0];
            float fg = acc[half * 4 + 1][j] + e[256];
            float gg = acc[half * 4 + 2][j] + e[512];
            float og = acc[half * 4 + 3][j] + e[768];
            float cc = sig_(fg) * coldp[j] + sig_(ig) * th_(gg);
            c4[j] = cc;
            h4[j] = sig_(og) * th_(cc);
            int p = scol + j;
            if (p >= a_t1 && p < a_t)      // len == t+1: last valid step
                featsT[u * 4096 + pns[j]] = h4[j];
        }
        *(float4*)&cT[u * 4096 + scol]     = make_float4(c4[0], c4[1], c4[2], c4[3]);
        *(float4*)&hTnext[u * 4096 + scol] = make_float4(h4[0], h4[1], h4[2], h4[3]);
    }
}

// ---------------------------------------------------------------------------
// T-GEMM 128r x 64s (8x4): Out[r][s] = sum_k W[r][k]*X[k*xstride+s] + add.
// Skewed w-LDS + double-buffered chunks (one barrier/chunk). grid (64, 8).
// Phase-2: X = hTbuf (HSTRIDE, front pad -> X[k][s] = h[k][s-1]).
// (Round-9 configuration — best measured.)
// ---------------------------------------------------------------------------
__global__ __launch_bounds__(256, 2)
void gemm_T(const float* __restrict__ W, const float* __restrict__ X, int xstride,
            const float* __restrict__ addm, const float* __restrict__ bias,
            float* __restrict__ Out)
{
    __shared__ float w_lds[2][32][140];
    __shared__ float h_lds[2][32][68];
    const int tid = threadIdx.x;
    const int tr = tid & 15;
    const int ts = tid >> 4;
    const int s0 = blockIdx.x * 64;
    const int r0 = blockIdx.y * 128;
    const int wphys = tr * 8 + ((tr >> 2) << 2);

    float acc[8][4];
    #pragma unroll
    for (int x = 0; x < 8; ++x)
        #pragma unroll
        for (int y = 0; y < 4; ++y) acc[x][y] = 0.f;

    float4 wbuf[4], hbuf[2];
    auto load_t = [&](int k0) {
        #pragma unroll
        for (int p = 0; p < 4; ++p) {
            int idx = tid + p * 256;
            int r = idx >> 3, k4 = idx & 7;
            wbuf[p] = *(const float4*)&W[(r0 + r) * 256 + k0 + k4 * 4];
        }
        #pragma unroll
        for (int p = 0; p < 2; ++p) {
            int idx = tid + p * 256;
            int jj = idx >> 4, s4 = idx & 15;
            hbuf[p] = *(const float4*)&X[(k0 + jj) * xstride + s0 + s4 * 4];
        }
    };
    auto store_t = [&](int b) {
        #pragma unroll
        for (int p = 0; p < 4; ++p) {
            int idx = tid + p * 256;
            int rl = idx >> 3, k4 = idx & 7;
            int pc = rl + ((rl >> 5) << 2);
            w_lds[b][k4 * 4 + 0][pc] = wbuf[p].x;
            w_lds[b][k4 * 4 + 1][pc] = wbuf[p].y;
            w_lds[b][k4 * 4 + 2][pc] = wbuf[p].z;
            w_lds[b][k4 * 4 + 3][pc] = wbuf[p].w;
        }
        #pragma unroll
        for (int p = 0; p < 2; ++p) {
            int idx = tid + p * 256;
            int jj = idx >> 4, s4 = idx & 15;
            *(float4*)&h_lds[b][jj][s4 * 4] = hbuf[p];
        }
    };

    load_t(0); store_t(0); __syncthreads();
    for (int c = 0; c < 8; ++c) {
        const int b = c & 1;
        if (c < 7) load_t((c + 1) * 32);
        #pragma unroll 4
        for (int k = 0; k < 32; ++k) {
            float4 w0 = *(const float4*)&w_lds[b][k][wphys];
            float4 w1 = *(const float4*)&w_lds[b][k][wphys + 4];
            float4 hv = *(const float4*)&h_lds[b][k][ts * 4];
            float wa[8] = {w0.x, w0.y, w0.z, w0.w, w1.x, w1.y, w1.z, w1.w};
            float ha[4] = {hv.x, hv.y, hv.z, hv.w};
            #pragma unroll
            for (int ri = 0; ri < 8; ++ri)
                #pragma unroll
                for (int si = 0; si < 4; ++si)
                    acc[ri][si] += wa[ri] * ha[si];
        }
        if (c < 7) store_t(b ^ 1);
        __syncthreads();
    }

    const int scol = s0 + ts * 4;
    #pragma unroll
    for (int ri = 0; ri < 8; ++ri) {
        const int r = r0 + tr * 8 + ri;
        float4 z;
        if (addm) {
            float4 gb = *(const float4*)&addm[r * 4096 + scol];
            z.x = acc[ri][0] + gb.x; z.y = acc[ri][1] + gb.y;
            z.z = acc[ri][2] + gb.z; z.w = acc[ri][3] + gb.w;
        } else {
            float bb = bias[r];
            z.x = acc[ri][0] + bb; z.y = acc[ri][1] + bb;
            z.z = acc[ri][2] + bb; z.w = acc[ri][3] + bb;
        }
        *(float4*)&Out[r * 4096 + scol] = z;
    }
}

// ---------------------------------------------------------------------------
// Sweep scan: exact per-unit affine scan of c given gate preactivations ZT,
// then h = sig(o)*tanh(c) -> hTbuf[u][1+s]. grid 256, block 256.
// ---------------------------------------------------------------------------
__global__ __launch_bounds__(256, 1)
void scan_sweep(const float* __restrict__ ZT, float* __restrict__ hTbuf)
{
    const int u = blockIdx.x;
    const int t = threadIdx.x;
    const int s0 = t * 16;

    const float* zi = ZT + (0 * 256 + u) * 4096 + s0;
    const float* zf = ZT + (1 * 256 + u) * 4096 + s0;
    const float* zg = ZT + (2 * 256 + u) * 4096 + s0;
    const float* zo = ZT + (3 * 256 + u) * 4096 + s0;

    float4 iv[4], fv[4], gv[4], ov[4];
    #pragma unroll
    for (int p = 0; p < 4; ++p) {
        iv[p] = *(const float4*)&zi[p * 4];
        fv[p] = *(const float4*)&zf[p * 4];
        gv[p] = *(const float4*)&zg[p * 4];
        ov[p] = *(const float4*)&zo[p * 4];
    }
    float af[16], uu[16];
    const float* ivp = (const float*)iv;
    const float* fvp = (const float*)fv;
    const float* gvp = (const float*)gv;
    float A = 1.f, U = 0.f;
    #pragma unroll
    for (int k = 0; k < 16; ++k) {
        af[k] = sig_(fvp[k]);
        uu[k] = sig_(ivp[k]) * th_(gvp[k]);
        U = af[k] * U + uu[k];
        A = af[k] * A;
    }

    __shared__ float As[256], Us[256];
    As[t] = A; Us[t] = U;
    __syncthreads();
    #pragma unroll
    for (int off = 1; off < 256; off <<= 1) {
        float eA = 1.f, eU = 0.f;
        if (t >= off) { eA = As[t - off]; eU = Us[t - off]; }
        __syncthreads();
        U = A * eU + U;
        A = A * eA;
        As[t] = A; Us[t] = U;
        __syncthreads();
    }
    float c = (t > 0) ? Us[t - 1] : 0.f;  // exclusive prefix -> entry c

    float* hp = hTbuf + u * HSTRIDE + 1 + s0;
    const float* ovp = (const float*)ov;
    #pragma unroll
    for (int k = 0; k < 16; ++k) {
        c = af[k] * c + uu[k];
        hp[k] = sig_(ovp[k]) * th_(c);
    }
}

// ---------------------------------------------------------------------------
// Final linear: out = h[4095] . lin_W + lin_b
// ---------------------------------------------------------------------------
__global__ __launch_bounds__(256)
void out_kernel(const float* __restrict__ hTbuf, const float* __restrict__ linW,
                const float* __restrict__ linb, float* __restrict__ out)
{
    const int tid = threadIdx.x;
    __shared__ float red_lds[4];
    float p = hTbuf[tid * HSTRIDE + 4096] * linW[tid];
    #pragma unroll
    for (int off = 1; off < 64; off <<= 1) p += __shfl_xor(p, off);
    if ((tid & 63) == 0) red_lds[tid >> 6] = p;
    __syncthreads();
    if (tid == 0)
        out[0] = red_lds[0] + red_lds[1] + red_lds[2] + red_lds[3] + linb[0];
}

extern "C" void kernel_launch(void* const* d_in, const int* in_sizes, int n_in,
                              void* d_out, int out_size, void* d_ws, size_t ws_size,
                              hipStream_t stream)
{
    const int*   tok  = (const int*)d_in[0];
    const int*   len  = (const int*)d_in[1];
    const float* emb  = (const float*)d_in[2];
    const float* tWih = (const float*)d_in[3];
    const float* tWhh = (const float*)d_in[4];
    const float* tb   = (const float*)d_in[5];
    const float* iWih = (const float*)d_in[6];
    const float* iWhh = (const float*)d_in[7];
    const float* ib   = (const float*)d_in[8];
    const float* lW   = (const float*)d_in[9];
    const float* lb   = (const float*)d_in[10];
    float* out = (float*)d_out;

    // workspace (floats), ~44 MB; ZT (phase 2) aliases hT0..featsT (dead)
    float* emb2   = (float*)d_ws;           // [2000][1024]   8 MB
    float* hT0    = emb2   + 2048000;       // [256][4096]    4 MB
    float* hT1    = hT0    + 1048576;       // [256][4096]
    float* cT     = hT1    + 1048576;       // [256][4096]
    float* featsT = cT     + 1048576;       // [256][4096]
    float* gBT    = featsT + 1048576;       // [1024][4096]  16 MB
    float* hTbuf  = gBT    + 4194304;       // [256][HSTRIDE], col0 = 0 pad
    int*   perm   = (int*)(hTbuf + 256 * HSTRIDE);  // [4096]
    int*   actcnt = perm + 4096;            // [17]
    float* ZT     = hT0;                    // [1024][4096] alias (phase 2 only)

    // hTbuf col 0 must be 0 (h[-1])
    hipMemsetAsync(hTbuf, 0, (size_t)256 * HSTRIDE * sizeof(float), stream);

    // ---- phase 1: token LSTM, transposed, length-sorted batch-parallel ----
    sortlen<<<1, 256, 0, stream>>>(len, perm, actcnt);
    gemm_emb2<<<dim3(32, 16), 256, 0, stream>>>(emb, tWih, tb, emb2, 2000);
    step0T<<<dim3(64, 16), 256, 0, stream>>>(tok, perm, actcnt, emb2, cT, hT0,
                                             featsT);
    for (int t = 1; t < 16; ++t) {
        float* hprev = (t & 1) ? hT0 : hT1;
        float* hcur  = (t & 1) ? hT1 : hT0;
        stepT<<<dim3(64, 8), 256, 0, stream>>>(tWhh, hprev, tok, t, emb2, perm,
                                               actcnt, cT, hcur, featsT);
    }
    // gBT[r][s] = ins_W_ih . featsT + ins_b
    gemm_T<<<dim3(64, 8), 256, 0, stream>>>(iWih, featsT, 4096, nullptr, ib, gBT);

    // ---- phase 2: fixed-point sweeps (no cross-block sync) ----
    scan_sweep<<<256, 256, 0, stream>>>(gBT, hTbuf);    // sweep 1: h_old = 0
    for (int k = 1; k < SWEEPS; ++k) {
        gemm_T<<<dim3(64, 8), 256, 0, stream>>>(iWhh, hTbuf, HSTRIDE, gBT,
                                                nullptr, ZT);
        scan_sweep<<<256, 256, 0, stream>>>(ZT, hTbuf);
    }

    out_kernel<<<1, 256, 0, stream>>>(hTbuf, lW, lb, out);
}

// Round 13
// 930.224 us; speedup vs baseline: 1.5905x; 1.0918x over previous
//
#include <hip/hip_runtime.h>

#define SWEEPS 6
#define HSTRIDE 4112   // hTbuf row stride: 4096 + front pad(1) + slack, %4==0

__device__ __forceinline__ float sig_(float x) { return 1.0f / (1.0f + __expf(-x)); }
__device__ __forceinline__ float th_(float x)  { return 1.0f - 2.0f / (__expf(2.0f * x) + 1.0f); }

// async global->LDS, 16B per lane. LDS dest rule: wave-uniform base + lane*16
// (caller must guarantee dest = base + idx*16 with idx = tid + p*256).
__device__ __forceinline__ void gload_lds16(const float* g, float* l) {
    __builtin_amdgcn_global_load_lds(
        (const __attribute__((address_space(1))) unsigned*)g,
        (__attribute__((address_space(3))) unsigned*)l, 16, 0, 0);
}

// ---------------------------------------------------------------------------
// emb2 build: emb2[v][j] = sum_k emb[v][k]*tWih[j][k] + tb[j]   (j = 0..1023)
// grid (32, 16), block 256, tile 64v x 64j, 4x4 microtile. 512 blocks.
// ---------------------------------------------------------------------------
__global__ __launch_bounds__(256, 2)
void gemm_emb2(const float* __restrict__ A, const float* __restrict__ Wt,
               const float* __restrict__ bias, float* __restrict__ Cout, int M)
{
    __shared__ float a_lds[32][68];
    __shared__ float b_lds[32][68];
    const int tid = threadIdx.x;
    const int tn = tid & 15;
    const int th = tid >> 4;
    const int m0 = blockIdx.x * 64;
    const int j0 = blockIdx.y * 64;

    float acc[4][4];
    #pragma unroll
    for (int x = 0; x < 4; ++x)
        #pragma unroll
        for (int y = 0; y < 4; ++y) acc[x][y] = 0.f;

    float4 abuf[2], bbuf[2];
    auto load_t = [&](int k0) {
        #pragma unroll
        for (int p = 0; p < 2; ++p) {
            int idx = tid + p * 256, ml = idx >> 3, k4 = idx & 7;
            int row = m0 + ml;
            abuf[p] = (row < M) ? *(const float4*)&A[row * 256 + k0 + k4 * 4]
                                : make_float4(0.f, 0.f, 0.f, 0.f);
            bbuf[p] = *(const float4*)&Wt[(j0 + ml) * 256 + k0 + k4 * 4];
        }
    };
    auto store_t = [&]() {
        #pragma unroll
        for (int p = 0; p < 2; ++p) {
            int idx = tid + p * 256, ml = idx >> 3, k4 = idx & 7;
            a_lds[k4 * 4 + 0][ml] = abuf[p].x;
            a_lds[k4 * 4 + 1][ml] = abuf[p].y;
            a_lds[k4 * 4 + 2][ml] = abuf[p].z;
            a_lds[k4 * 4 + 3][ml] = abuf[p].w;
            b_lds[k4 * 4 + 0][ml] = bbuf[p].x;
            b_lds[k4 * 4 + 1][ml] = bbuf[p].y;
            b_lds[k4 * 4 + 2][ml] = bbuf[p].z;
            b_lds[k4 * 4 + 3][ml] = bbuf[p].w;
        }
    };

    load_t(0); store_t(); __syncthreads();
    for (int c = 0; c < 8; ++c) {
        if (c < 7) load_t((c + 1) * 32);
        #pragma unroll 8
        for (int k = 0; k < 32; ++k) {
            float4 a4 = *(const float4*)&a_lds[k][tn * 4];
            float4 b4 = *(const float4*)&b_lds[k][th * 4];
            float av[4] = {a4.x, a4.y, a4.z, a4.w};
            float bv[4] = {b4.x, b4.y, b4.z, b4.w};
            #pragma unroll
            for (int mi = 0; mi < 4; ++mi)
                #pragma unroll
                for (int ji = 0; ji < 4; ++ji)
                    acc[mi][ji] += av[mi] * bv[ji];
        }
        __syncthreads();
        if (c < 7) { store_t(); __syncthreads(); }
    }

    const int jcol = j0 + th * 4;
    float4 bs = *(const float4*)&bias[jcol];
    #pragma unroll
    for (int mi = 0; mi < 4; ++mi) {
        int row = m0 + tn * 4 + mi;
        if (row < M) {
            float4 o;
            o.x = acc[mi][0] + bs.x;
            o.y = acc[mi][1] + bs.y;
            o.z = acc[mi][2] + bs.z;
            o.w = acc[mi][3] + bs.w;
            *(float4*)&Cout[row * 1024 + jcol] = o;
        }
    }
}

// ---------------------------------------------------------------------------
// Counting sort of sequences by length, DESCENDING. One block.
// perm[p] = original n of sorted slot p; actcnt[t] = #{n : len[n] > t}.
// ---------------------------------------------------------------------------
__global__ __launch_bounds__(256)
void sortlen(const int* __restrict__ len, int* __restrict__ perm,
             int* __restrict__ actcnt)
{
    __shared__ int cnt[17], off[17];
    const int tid = threadIdx.x;
    if (tid < 17) cnt[tid] = 0;
    __syncthreads();
    for (int n = tid; n < 4096; n += 256) atomicAdd(&cnt[len[n]], 1);
    __syncthreads();
    if (tid == 0) {
        int run = 0;
        for (int L = 16; L >= 1; --L) { off[L] = run; run += cnt[L]; }
        actcnt[16] = 0;
        for (int t = 1; t < 16; ++t) actcnt[t] = off[t];
        actcnt[0] = 4096;
    }
    __syncthreads();
    for (int n = tid; n < 4096; n += 256) {
        int pos = atomicAdd(&off[len[n]], 1);
        perm[pos] = n;
    }
}

// ---------------------------------------------------------------------------
// Token-LSTM step 0 (h0=c0=0 -> pointwise emb2 gather), TRANSPOSED + sorted.
// ---------------------------------------------------------------------------
__global__ __launch_bounds__(256)
void step0T(const int* __restrict__ tok, const int* __restrict__ perm,
            const int* __restrict__ actcnt, const float* __restrict__ emb2,
            float* __restrict__ cT, float* __restrict__ hT0,
            float* __restrict__ featsT)
{
    const int tid = threadIdx.x;
    const int tn = tid & 15, tu = tid >> 4;
    const int u  = blockIdx.y * 16 + tu;
    const int n0 = blockIdx.x * 64 + tn * 4;
    const int a1 = actcnt[1];
    int4 pn = *(const int4*)&perm[n0];
    const int pns[4] = {pn.x, pn.y, pn.z, pn.w};
    float h4[4], c4[4];
    #pragma unroll
    for (int j = 0; j < 4; ++j) {
        int v = tok[pns[j] * 16];
        const float* e = emb2 + v * 1024 + u;
        float ig = e[0], gg = e[512], og = e[768];
        float c = sig_(ig) * th_(gg);
        float h = sig_(og) * th_(c);
        c4[j] = c; h4[j] = h;
        if (n0 + j >= a1) featsT[u * 4096 + pns[j]] = h;   // len == 1
    }
    *(float4*)&cT[u * 4096 + n0]  = make_float4(c4[0], c4[1], c4[2], c4[3]);
    *(float4*)&hT0[u * 4096 + n0] = make_float4(h4[0], h4[1], h4[2], h4[3]);
}

// ---------------------------------------------------------------------------
// Token-LSTM step t (t>=1), fused, TRANSPOSED, sorted, 128r x 64s (8x4).
// Early-exit on actcnt. w-LDS skew: phys col = rl + 4*(rl>>5).
// h staged via async global_load_lds width=16 (dest = base + idx*16; pad
// dropped to satisfy the lane-contiguity rule; reads stay 2-way = free).
// Double-buffered chunks, one barrier per chunk.
// ---------------------------------------------------------------------------
__global__ __launch_bounds__(256, 2)
void stepT(const float* __restrict__ Whh, const float* __restrict__ hTprev,
           const int* __restrict__ tok, int t, const float* __restrict__ emb2,
           const int* __restrict__ perm, const int* __restrict__ actcnt,
           float* __restrict__ cT, float* __restrict__ hTnext,
           float* __restrict__ featsT)
{
    const int s0 = blockIdx.x * 64;
    const int a_t  = actcnt[t];
    if (s0 >= a_t) return;                // inactive tile: all lengths <= t
    const int a_t1 = actcnt[t + 1];

    __shared__ float w_lds[2][32][140];   // [buf][k][phys(rl)], skewed
    __shared__ float h_lds[2][32][64];    // [buf][k][s] (unpadded: async dest)
    const int tid = threadIdx.x;
    const int tr = tid & 15;              // r-octet
    const int ts = tid >> 4;              // s-quad
    const int ub = blockIdx.y;            // unit-tile (32 units)
    const int scol = s0 + ts * 4;
    const int wphys = tr * 8 + ((tr >> 2) << 2);

    // prefetch epilogue inputs early (independent of GEMM)
    int4 pn = *(const int4*)&perm[scol];
    const int pns[4] = {pn.x, pn.y, pn.z, pn.w};
    int vids[4];
    #pragma unroll
    for (int j = 0; j < 4; ++j) vids[j] = tok[pns[j] * 16 + t];

    float acc[8][4];
    #pragma unroll
    for (int x = 0; x < 8; ++x)
        #pragma unroll
        for (int y = 0; y < 4; ++y) acc[x][y] = 0.f;

    float4 wbuf[4];
    auto load_w = [&](int k0) {
        #pragma unroll
        for (int p = 0; p < 4; ++p) {
            int idx = tid + p * 256;
            int rl = idx >> 3, k4 = idx & 7;
            int gi = rl & 3, ii = rl >> 2;
            wbuf[p] = *(const float4*)&Whh[(gi * 256 + ub * 32 + ii) * 256 + k0 + k4 * 4];
        }
    };
    auto load_h = [&](int k0, int b) {    // async: dest = base + idx*16
        #pragma unroll
        for (int p = 0; p < 2; ++p) {
            int idx = tid + p * 256;
            int jj = idx >> 4, s4 = idx & 15;
            gload_lds16(&hTprev[(k0 + jj) * 4096 + s0 + s4 * 4],
                        &h_lds[b][jj][s4 * 4]);
        }
    };
    auto store_w = [&](int b) {
        #pragma unroll
        for (int p = 0; p < 4; ++p) {
            int idx = tid + p * 256;
            int rl = idx >> 3, k4 = idx & 7;
            int pc = rl + ((rl >> 5) << 2);
            w_lds[b][k4 * 4 + 0][pc] = wbuf[p].x;
            w_lds[b][k4 * 4 + 1][pc] = wbuf[p].y;
            w_lds[b][k4 * 4 + 2][pc] = wbuf[p].z;
            w_lds[b][k4 * 4 + 3][pc] = wbuf[p].w;
        }
    };

    load_w(0); load_h(0, 0); store_w(0); __syncthreads();
    for (int c = 0; c < 8; ++c) {
        const int b = c & 1;
        if (c < 7) { load_w((c + 1) * 32); load_h((c + 1) * 32, b ^ 1); }
        #pragma unroll 4
        for (int k = 0; k < 32; ++k) {
            float4 w0 = *(const float4*)&w_lds[b][k][wphys];
            float4 w1 = *(const float4*)&w_lds[b][k][wphys + 4];
            float4 hv = *(const float4*)&h_lds[b][k][ts * 4];
            float wa[8] = {w0.x, w0.y, w0.z, w0.w, w1.x, w1.y, w1.z, w1.w};
            float ha[4] = {hv.x, hv.y, hv.z, hv.w};
            #pragma unroll
            for (int ri = 0; ri < 8; ++ri)
                #pragma unroll
                for (int si = 0; si < 4; ++si)
                    acc[ri][si] += wa[ri] * ha[si];
        }
        if (c < 7) store_w(b ^ 1);        // other buffer: no WAR hazard
        __syncthreads();                  // drains vmcnt (async h) + barrier
    }

    // epilogue: 2 units x 4 slots LSTM update
    #pragma unroll
    for (int half = 0; half < 2; ++half) {
        const int u = ub * 32 + tr * 2 + half;
        float4 cold = *(const float4*)&cT[u * 4096 + scol];
        const float* coldp = (const float*)&cold;
        float c4[4], h4[4];
        #pragma unroll
        for (int j = 0; j < 4; ++j) {
            const float* e = emb2 + vids[j] * 1024 + u;
            float ig = acc[half * 4 + 0][j] + e[0];
            float fg = acc[half * 4 + 1][j] + e[256];
            float gg = acc[half * 4 + 2][j] + e[512];
            float og = acc[half * 4 + 3][j] + e[768];
            float cc = sig_(fg) * coldp[j] + sig_(ig) * th_(gg);
            c4[j] = cc;
            h4[j] = sig_(og) * th_(cc);
            int p = scol + j;
            if (p >= a_t1 && p < a_t)      // len == t+1: last valid step
                featsT[u * 4096 + pns[j]] = h4[j];
        }
        *(float4*)&cT[u * 4096 + scol]     = make_float4(c4[0], c4[1], c4[2], c4[3]);
        *(float4*)&hTnext[u * 4096 + scol] = make_float4(h4[0], h4[1], h4[2], h4[3]);
    }
}

// ---------------------------------------------------------------------------
// T-GEMM 128r x 64s (8x4): Out[r][s] = sum_k W[r][k]*X[k*xstride+s] + add.
// Skewed w-LDS; h via async global_load_lds (unpadded). grid (64, 8).
// Phase-2: X = hTbuf (HSTRIDE, front pad -> X[k][s] = h[k][s-1]).
// ---------------------------------------------------------------------------
__global__ __launch_bounds__(256, 2)
void gemm_T(const float* __restrict__ W, const float* __restrict__ X, int xstride,
            const float* __restrict__ addm, const float* __restrict__ bias,
            float* __restrict__ Out)
{
    __shared__ float w_lds[2][32][140];
    __shared__ float h_lds[2][32][64];
    const int tid = threadIdx.x;
    const int tr = tid & 15;
    const int ts = tid >> 4;
    const int s0 = blockIdx.x * 64;
    const int r0 = blockIdx.y * 128;
    const int wphys = tr * 8 + ((tr >> 2) << 2);

    float acc[8][4];
    #pragma unroll
    for (int x = 0; x < 8; ++x)
        #pragma unroll
        for (int y = 0; y < 4; ++y) acc[x][y] = 0.f;

    float4 wbuf[4];
    auto load_w = [&](int k0) {
        #pragma unroll
        for (int p = 0; p < 4; ++p) {
            int idx = tid + p * 256;
            int r = idx >> 3, k4 = idx & 7;
            wbuf[p] = *(const float4*)&W[(r0 + r) * 256 + k0 + k4 * 4];
        }
    };
    auto load_h = [&](int k0, int b) {
        #pragma unroll
        for (int p = 0; p < 2; ++p) {
            int idx = tid + p * 256;
            int jj = idx >> 4, s4 = idx & 15;
            gload_lds16(&X[(k0 + jj) * xstride + s0 + s4 * 4],
                        &h_lds[b][jj][s4 * 4]);
        }
    };
    auto store_w = [&](int b) {
        #pragma unroll
        for (int p = 0; p < 4; ++p) {
            int idx = tid + p * 256;
            int rl = idx >> 3, k4 = idx & 7;
            int pc = rl + ((rl >> 5) << 2);
            w_lds[b][k4 * 4 + 0][pc] = wbuf[p].x;
            w_lds[b][k4 * 4 + 1][pc] = wbuf[p].y;
            w_lds[b][k4 * 4 + 2][pc] = wbuf[p].z;
            w_lds[b][k4 * 4 + 3][pc] = wbuf[p].w;
        }
    };

    load_w(0); load_h(0, 0); store_w(0); __syncthreads();
    for (int c = 0; c < 8; ++c) {
        const int b = c & 1;
        if (c < 7) { load_w((c + 1) * 32); load_h((c + 1) * 32, b ^ 1); }
        #pragma unroll 4
        for (int k = 0; k < 32; ++k) {
            float4 w0 = *(const float4*)&w_lds[b][k][wphys];
            float4 w1 = *(const float4*)&w_lds[b][k][wphys + 4];
            float4 hv = *(const float4*)&h_lds[b][k][ts * 4];
            float wa[8] = {w0.x, w0.y, w0.z, w0.w, w1.x, w1.y, w1.z, w1.w};
            float ha[4] = {hv.x, hv.y, hv.z, hv.w};
            #pragma unroll
            for (int ri = 0; ri < 8; ++ri)
                #pragma unroll
                for (int si = 0; si < 4; ++si)
                    acc[ri][si] += wa[ri] * ha[si];
        }
        if (c < 7) store_w(b ^ 1);
        __syncthreads();
    }

    const int scol = s0 + ts * 4;
    #pragma unroll
    for (int ri = 0; ri < 8; ++ri) {
        const int r = r0 + tr * 8 + ri;
        float4 z;
        if (addm) {
            float4 gb = *(const float4*)&addm[r * 4096 + scol];
            z.x = acc[ri][0] + gb.x; z.y = acc[ri][1] + gb.y;
            z.z = acc[ri][2] + gb.z; z.w = acc[ri][3] + gb.w;
        } else {
            float bb = bias[r];
            z.x = acc[ri][0] + bb; z.y = acc[ri][1] + bb;
            z.z = acc[ri][2] + bb; z.w = acc[ri][3] + bb;
        }
        *(float4*)&Out[r * 4096 + scol] = z;
    }
}

// ---------------------------------------------------------------------------
// Sweep scan: exact per-unit affine scan of c given gate preactivations ZT,
// then h = sig(o)*tanh(c) -> hTbuf[u][1+s]. grid 256, block 256.
// ---------------------------------------------------------------------------
__global__ __launch_bounds__(256, 1)
void scan_sweep(const float* __restrict__ ZT, float* __restrict__ hTbuf)
{
    const int u = blockIdx.x;
    const int t = threadIdx.x;
    const int s0 = t * 16;

    const float* zi = ZT + (0 * 256 + u) * 4096 + s0;
    const float* zf = ZT + (1 * 256 + u) * 4096 + s0;
    const float* zg = ZT + (2 * 256 + u) * 4096 + s0;
    const float* zo = ZT + (3 * 256 + u) * 4096 + s0;

    float4 iv[4], fv[4], gv[4], ov[4];
    #pragma unroll
    for (int p = 0; p < 4; ++p) {
        iv[p] = *(const float4*)&zi[p * 4];
        fv[p] = *(const float4*)&zf[p * 4];
        gv[p] = *(const float4*)&zg[p * 4];
        ov[p] = *(const float4*)&zo[p * 4];
    }
    float af[16], uu[16];
    const float* ivp = (const float*)iv;
    const float* fvp = (const float*)fv;
    const float* gvp = (const float*)gv;
    float A = 1.f, U = 0.f;
    #pragma unroll
    for (int k = 0; k < 16; ++k) {
        af[k] = sig_(fvp[k]);
        uu[k] = sig_(ivp[k]) * th_(gvp[k]);
        U = af[k] * U + uu[k];
        A = af[k] * A;
    }

    __shared__ float As[256], Us[256];
    As[t] = A; Us[t] = U;
    __syncthreads();
    #pragma unroll
    for (int off = 1; off < 256; off <<= 1) {
        float eA = 1.f, eU = 0.f;
        if (t >= off) { eA = As[t - off]; eU = Us[t - off]; }
        __syncthreads();
        U = A * eU + U;
        A = A * eA;
        As[t] = A; Us[t] = U;
        __syncthreads();
    }
    float c = (t > 0) ? Us[t - 1] : 0.f;  // exclusive prefix -> entry c

    float* hp = hTbuf + u * HSTRIDE + 1 + s0;
    const float* ovp = (const float*)ov;
    #pragma unroll
    for (int k = 0; k < 16; ++k) {
        c = af[k] * c + uu[k];
        hp[k] = sig_(ovp[k]) * th_(c);
    }
}

// ---------------------------------------------------------------------------
// Final linear: out = h[4095] . lin_W + lin_b
// ---------------------------------------------------------------------------
__global__ __launch_bounds__(256)
void out_kernel(const float* __restrict__ hTbuf, const float* __restrict__ linW,
                const float* __restrict__ linb, float* __restrict__ out)
{
    const int tid = threadIdx.x;
    __shared__ float red_lds[4];
    float p = hTbuf[tid * HSTRIDE + 4096] * linW[tid];
    #pragma unroll
    for (int off = 1; off < 64; off <<= 1) p += __shfl_xor(p, off);
    if ((tid & 63) == 0) red_lds[tid >> 6] = p;
    __syncthreads();
    if (tid == 0)
        out[0] = red_lds[0] + red_lds[1] + red_lds[2] + red_lds[3] + linb[0];
}

extern "C" void kernel_launch(void* const* d_in, const int* in_sizes, int n_in,
                              void* d_out, int out_size, void* d_ws, size_t ws_size,
                              hipStream_t stream)
{
    const int*   tok  = (const int*)d_in[0];
    const int*   len  = (const int*)d_in[1];
    const float* emb  = (const float*)d_in[2];
    const float* tWih = (const float*)d_in[3];
    const float* tWhh = (const float*)d_in[4];
    const float* tb   = (const float*)d_in[5];
    const float* iWih = (const float*)d_in[6];
    const float* iWhh = (const float*)d_in[7];
    const float* ib   = (const float*)d_in[8];
    const float* lW   = (const float*)d_in[9];
    const float* lb   = (const float*)d_in[10];
    float* out = (float*)d_out;

    // workspace (floats), ~44 MB; ZT (phase 2) aliases hT0..featsT (dead)
    float* emb2   = (float*)d_ws;           // [2000][1024]   8 MB
    float* hT0    = emb2   + 2048000;       // [256][4096]    4 MB
    float* hT1    = hT0    + 1048576;       // [256][4096]
    float* cT     = hT1    + 1048576;       // [256][4096]
    float* featsT = cT     + 1048576;       // [256][4096]
    float* gBT    = featsT + 1048576;       // [1024][4096]  16 MB
    float* hTbuf  = gBT    + 4194304;       // [256][HSTRIDE], col0 = 0 pad
    int*   perm   = (int*)(hTbuf + 256 * HSTRIDE);  // [4096]
    int*   actcnt = perm + 4096;            // [17]
    float* ZT     = hT0;                    // [1024][4096] alias (phase 2 only)

    // hTbuf col 0 must be 0 (h[-1])
    hipMemsetAsync(hTbuf, 0, (size_t)256 * HSTRIDE * sizeof(float), stream);

    // ---- phase 1: token LSTM, transposed, length-sorted batch-parallel ----
    sortlen<<<1, 256, 0, stream>>>(len, perm, actcnt);
    gemm_emb2<<<dim3(32, 16), 256, 0, stream>>>(emb, tWih, tb, emb2, 2000);
    step0T<<<dim3(64, 16), 256, 0, stream>>>(tok, perm, actcnt, emb2, cT, hT0,
                                             featsT);
    for (int t = 1; t < 16; ++t) {
        float* hprev = (t & 1) ? hT0 : hT1;
        float* hcur  = (t & 1) ? hT1 : hT0;
        stepT<<<dim3(64, 8), 256, 0, stream>>>(tWhh, hprev, tok, t, emb2, perm,
                                               actcnt, cT, hcur, featsT);
    }
    // gBT[r][s] = ins_W_ih . featsT + ins_b
    gemm_T<<<dim3(64, 8), 256, 0, stream>>>(iWih, featsT, 4096, nullptr, ib, gBT);

    // ---- phase 2: fixed-point sweeps (no cross-block sync) ----
    scan_sweep<<<256, 256, 0, stream>>>(gBT, hTbuf);    // sweep 1: h_old = 0
    for (int k = 1; k < SWEEPS; ++k) {
        gemm_T<<<dim3(64, 8), 256, 0, stream>>>(iWhh, hTbuf, HSTRIDE, gBT,
                                                nullptr, ZT);
        scan_sweep<<<256, 256, 0, stream>>>(ZT, hTbuf);
    }

    out_kernel<<<1, 256, 0, stream>>>(hTbuf, lW, lb, out);
}

// Round 14
// 898.361 us; speedup vs baseline: 1.6469x; 1.0355x over previous
//
#include <hip/hip_runtime.h>

#define SWEEPS 6
#define HSTRIDE 4112   // hTbuf row stride: 4096 + front pad(1) + slack, %4==0
#define WROW 140       // skewed W image row: pc(rl) = rl + 4*(rl>>5), max 139
#define WTSZ (8 * 256 * WROW)   // one W image: 8 rtiles x 256 k x 140

__device__ __forceinline__ float sig_(float x) { return 1.0f / (1.0f + __expf(-x)); }
__device__ __forceinline__ float th_(float x)  { return 1.0f - 2.0f / (__expf(2.0f * x) + 1.0f); }

// async global->LDS, 16B per lane. LDS dest rule: wave-uniform base + lane*16.
__device__ __forceinline__ void gload_lds16(const float* g, float* l) {
    __builtin_amdgcn_global_load_lds(
        (const __attribute__((address_space(1))) unsigned*)g,
        (__attribute__((address_space(3))) unsigned*)l, 16, 0, 0);
}

// ---------------------------------------------------------------------------
// W image builder: WT[rt][k][pc(rl)] = W[rowmap(rt,rl)][k], rowmap linear
// (ilv=0) or LSTM gate-interleaved rl=ii*4+gi (ilv=1). Runs once per matrix.
// grid (8 kchunks, 8 rtiles), block 256. Gap columns hold garbage (never read).
// ---------------------------------------------------------------------------
__global__ __launch_bounds__(256)
void wtrans(const float* __restrict__ W, float* __restrict__ WT, int ilv)
{
    __shared__ float s[32 * WROW];
    const int tid = threadIdx.x;
    const int k0 = blockIdx.x * 32;
    const int rt = blockIdx.y;
    #pragma unroll
    for (int p = 0; p < 4; ++p) {
        int idx = tid + p * 256;
        int rl = idx >> 3, k4 = idx & 7;
        int row = ilv ? ((rl & 3) * 256 + rt * 32 + (rl >> 2))
                      : (rt * 128 + rl);
        float4 v = *(const float4*)&W[row * 256 + k0 + k4 * 4];
        int pc = rl + ((rl >> 5) << 2);
        s[(k4 * 4 + 0) * WROW + pc] = v.x;
        s[(k4 * 4 + 1) * WROW + pc] = v.y;
        s[(k4 * 4 + 2) * WROW + pc] = v.z;
        s[(k4 * 4 + 3) * WROW + pc] = v.w;
    }
    __syncthreads();
    float* dst = WT + (size_t)(rt * 256 + k0) * WROW;
    for (int i = tid; i < 32 * WROW; i += 256) dst[i] = s[i];
}

// ---------------------------------------------------------------------------
// emb2 build: emb2[v][j] = sum_k emb[v][k]*tWih[j][k] + tb[j]   (j = 0..1023)
// grid (32, 16), block 256, tile 64v x 64j, 4x4 microtile. 512 blocks.
// ---------------------------------------------------------------------------
__global__ __launch_bounds__(256, 2)
void gemm_emb2(const float* __restrict__ A, const float* __restrict__ Wt,
               const float* __restrict__ bias, float* __restrict__ Cout, int M)
{
    __shared__ float a_lds[32][68];
    __shared__ float b_lds[32][68];
    const int tid = threadIdx.x;
    const int tn = tid & 15;
    const int th = tid >> 4;
    const int m0 = blockIdx.x * 64;
    const int j0 = blockIdx.y * 64;

    float acc[4][4];
    #pragma unroll
    for (int x = 0; x < 4; ++x)
        #pragma unroll
        for (int y = 0; y < 4; ++y) acc[x][y] = 0.f;

    float4 abuf[2], bbuf[2];
    auto load_t = [&](int k0) {
        #pragma unroll
        for (int p = 0; p < 2; ++p) {
            int idx = tid + p * 256, ml = idx >> 3, k4 = idx & 7;
            int row = m0 + ml;
            abuf[p] = (row < M) ? *(const float4*)&A[row * 256 + k0 + k4 * 4]
                                : make_float4(0.f, 0.f, 0.f, 0.f);
            bbuf[p] = *(const float4*)&Wt[(j0 + ml) * 256 + k0 + k4 * 4];
        }
    };
    auto store_t = [&]() {
        #pragma unroll
        for (int p = 0; p < 2; ++p) {
            int idx = tid + p * 256, ml = idx >> 3, k4 = idx & 7;
            a_lds[k4 * 4 + 0][ml] = abuf[p].x;
            a_lds[k4 * 4 + 1][ml] = abuf[p].y;
            a_lds[k4 * 4 + 2][ml] = abuf[p].z;
            a_lds[k4 * 4 + 3][ml] = abuf[p].w;
            b_lds[k4 * 4 + 0][ml] = bbuf[p].x;
            b_lds[k4 * 4 + 1][ml] = bbuf[p].y;
            b_lds[k4 * 4 + 2][ml] = bbuf[p].z;
            b_lds[k4 * 4 + 3][ml] = bbuf[p].w;
        }
    };

    load_t(0); store_t(); __syncthreads();
    for (int c = 0; c < 8; ++c) {
        if (c < 7) load_t((c + 1) * 32);
        #pragma unroll 8
        for (int k = 0; k < 32; ++k) {
            float4 a4 = *(const float4*)&a_lds[k][tn * 4];
            float4 b4 = *(const float4*)&b_lds[k][th * 4];
            float av[4] = {a4.x, a4.y, a4.z, a4.w};
            float bv[4] = {b4.x, b4.y, b4.z, b4.w};
            #pragma unroll
            for (int mi = 0; mi < 4; ++mi)
                #pragma unroll
                for (int ji = 0; ji < 4; ++ji)
                    acc[mi][ji] += av[mi] * bv[ji];
        }
        __syncthreads();
        if (c < 7) { store_t(); __syncthreads(); }
    }

    const int jcol = j0 + th * 4;
    float4 bs = *(const float4*)&bias[jcol];
    #pragma unroll
    for (int mi = 0; mi < 4; ++mi) {
        int row = m0 + tn * 4 + mi;
        if (row < M) {
            float4 o;
            o.x = acc[mi][0] + bs.x;
            o.y = acc[mi][1] + bs.y;
            o.z = acc[mi][2] + bs.z;
            o.w = acc[mi][3] + bs.w;
            *(float4*)&Cout[row * 1024 + jcol] = o;
        }
    }
}

// ---------------------------------------------------------------------------
// Counting sort of sequences by length, DESCENDING. One block.
// ---------------------------------------------------------------------------
__global__ __launch_bounds__(256)
void sortlen(const int* __restrict__ len, int* __restrict__ perm,
             int* __restrict__ actcnt)
{
    __shared__ int cnt[17], off[17];
    const int tid = threadIdx.x;
    if (tid < 17) cnt[tid] = 0;
    __syncthreads();
    for (int n = tid; n < 4096; n += 256) atomicAdd(&cnt[len[n]], 1);
    __syncthreads();
    if (tid == 0) {
        int run = 0;
        for (int L = 16; L >= 1; --L) { off[L] = run; run += cnt[L]; }
        actcnt[16] = 0;
        for (int t = 1; t < 16; ++t) actcnt[t] = off[t];
        actcnt[0] = 4096;
    }
    __syncthreads();
    for (int n = tid; n < 4096; n += 256) {
        int pos = atomicAdd(&off[len[n]], 1);
        perm[pos] = n;
    }
}

// ---------------------------------------------------------------------------
// Token-LSTM step 0 (h0=c0=0 -> pointwise emb2 gather), TRANSPOSED + sorted.
// ---------------------------------------------------------------------------
__global__ __launch_bounds__(256)
void step0T(const int* __restrict__ tok, const int* __restrict__ perm,
            const int* __restrict__ actcnt, const float* __restrict__ emb2,
            float* __restrict__ cT, float* __restrict__ hT0,
            float* __restrict__ featsT)
{
    const int tid = threadIdx.x;
    const int tn = tid & 15, tu = tid >> 4;
    const int u  = blockIdx.y * 16 + tu;
    const int n0 = blockIdx.x * 64 + tn * 4;
    const int a1 = actcnt[1];
    int4 pn = *(const int4*)&perm[n0];
    const int pns[4] = {pn.x, pn.y, pn.z, pn.w};
    float h4[4], c4[4];
    #pragma unroll
    for (int j = 0; j < 4; ++j) {
        int v = tok[pns[j] * 16];
        const float* e = emb2 + v * 1024 + u;
        float ig = e[0], gg = e[512], og = e[768];
        float c = sig_(ig) * th_(gg);
        float h = sig_(og) * th_(c);
        c4[j] = c; h4[j] = h;
        if (n0 + j >= a1) featsT[u * 4096 + pns[j]] = h;   // len == 1
    }
    *(float4*)&cT[u * 4096 + n0]  = make_float4(c4[0], c4[1], c4[2], c4[3]);
    *(float4*)&hT0[u * 4096 + n0] = make_float4(h4[0], h4[1], h4[2], h4[3]);
}

// ---------------------------------------------------------------------------
// Token-LSTM step t (t>=1), fused, TRANSPOSED, sorted, 128r x 64s (8x4).
// W comes from the pre-transposed pre-skewed image (tWhhT, gate-interleaved):
// BOTH W and h stage via linear async global_load_lds width=16 -> zero
// ds_writes in the hot loop, zero transpose conflicts. Reads are the
// validated 2-way-free r9 pattern. Double-buffered, 1 barrier/chunk.
// ---------------------------------------------------------------------------
__global__ __launch_bounds__(256, 2)
void stepT(const float* __restrict__ WT, const float* __restrict__ hTprev,
           const int* __restrict__ tok, int t, const float* __restrict__ emb2,
           const int* __restrict__ perm, const int* __restrict__ actcnt,
           float* __restrict__ cT, float* __restrict__ hTnext,
           float* __restrict__ featsT)
{
    const int s0 = blockIdx.x * 64;
    const int a_t  = actcnt[t];
    if (s0 >= a_t) return;                // inactive tile: all lengths <= t
    const int a_t1 = actcnt[t + 1];

    __shared__ float w_lds[2][32 * WROW]; // skewed image chunk (as-is)
    __shared__ float h_lds[2][32][64];    // unpadded (async dest)
    const int tid = threadIdx.x;
    const int tr = tid & 15;              // r-octet
    const int ts = tid >> 4;              // s-quad
    const int ub = blockIdx.y;            // unit-tile (32 units)
    const int scol = s0 + ts * 4;
    const int wphys = tr * 8 + ((tr >> 2) << 2);

    // prefetch epilogue inputs early (independent of GEMM)
    int4 pn = *(const int4*)&perm[scol];
    const int pns[4] = {pn.x, pn.y, pn.z, pn.w};
    int vids[4];
    #pragma unroll
    for (int j = 0; j < 4; ++j) vids[j] = tok[pns[j] * 16 + t];

    float acc[8][4];
    #pragma unroll
    for (int x = 0; x < 8; ++x)
        #pragma unroll
        for (int y = 0; y < 4; ++y) acc[x][y] = 0.f;

    auto issue_w = [&](int c, int b) {    // 1120 16B units, linear stream
        const float* src = WT + (size_t)(ub * 256 + c * 32) * WROW;
        #pragma unroll
        for (int p = 0; p < 4; ++p) {
            int idx = tid + p * 256;
            gload_lds16(src + idx * 4, &w_lds[b][idx * 4]);
        }
        if (tid < 96) {
            int idx = 1024 + tid;
            gload_lds16(src + idx * 4, &w_lds[b][idx * 4]);
        }
    };
    auto issue_h = [&](int k0, int b) {
        #pragma unroll
        for (int p = 0; p < 2; ++p) {
            int idx = tid + p * 256;
            int jj = idx >> 4, s4 = idx & 15;
            gload_lds16(&hTprev[(k0 + jj) * 4096 + s0 + s4 * 4],
                        &h_lds[b][jj][s4 * 4]);
        }
    };

    issue_w(0, 0); issue_h(0, 0); __syncthreads();
    for (int c = 0; c < 8; ++c) {
        const int b = c & 1;
        if (c < 7) { issue_w(c + 1, b ^ 1); issue_h((c + 1) * 32, b ^ 1); }
        #pragma unroll 4
        for (int k = 0; k < 32; ++k) {
            float4 w0 = *(const float4*)&w_lds[b][k * WROW + wphys];
            float4 w1 = *(const float4*)&w_lds[b][k * WROW + wphys + 4];
            float4 hv = *(const float4*)&h_lds[b][k][ts * 4];
            float wa[8] = {w0.x, w0.y, w0.z, w0.w, w1.x, w1.y, w1.z, w1.w};
            float ha[4] = {hv.x, hv.y, hv.z, hv.w};
            #pragma unroll
            for (int ri = 0; ri < 8; ++ri)
                #pragma unroll
                for (int si = 0; si < 4; ++si)
                    acc[ri][si] += wa[ri] * ha[si];
        }
        __syncthreads();                  // drains async loads + barrier
    }

    // epilogue: 2 units x 4 slots LSTM update
    #pragma unroll
    for (int half = 0; half < 2; ++half) {
        const int u = ub * 32 + tr * 2 + half;
        float4 cold = *(const float4*)&cT[u * 4096 + scol];
        const float* coldp = (const float*)&cold;
        float c4[4], h4[4];
        #pragma unroll
        for (int j = 0; j < 4; ++j) {
            const float* e = emb2 + vids[j] * 1024 + u;
            float ig = acc[half * 4 + 0][j] + e[0];
            float fg = acc[half * 4 + 1][j] + e[256];
            float gg = acc[half * 4 + 2][j] + e[512];
            float og = acc[half * 4 + 3][j] + e[768];
            float cc = sig_(fg) * coldp[j] + sig_(ig) * th_(gg);
            c4[j] = cc;
            h4[j] = sig_(og) * th_(cc);
            int p = scol + j;
            if (p >= a_t1 && p < a_t)      // len == t+1: last valid step
                featsT[u * 4096 + pns[j]] = h4[j];
        }
        *(float4*)&cT[u * 4096 + scol]     = make_float4(c4[0], c4[1], c4[2], c4[3]);
        *(float4*)&hTnext[u * 4096 + scol] = make_float4(h4[0], h4[1], h4[2], h4[3]);
    }
}

// ---------------------------------------------------------------------------
// T-GEMM 128r x 64s (8x4) from pre-skewed W image (linear rowmap).
// Out[r][s] = sum_k W[r][k]*X[k*xstride+s] + addm[r][s] or bias[r].
// grid (64, 8). Phase-2: X = hTbuf (HSTRIDE, front pad = s-1 shift).
// ---------------------------------------------------------------------------
__global__ __launch_bounds__(256, 2)
void gemm_T(const float* __restrict__ WT, const float* __restrict__ X, int xstride,
            const float* __restrict__ addm, const float* __restrict__ bias,
            float* __restrict__ Out)
{
    __shared__ float w_lds[2][32 * WROW];
    __shared__ float h_lds[2][32][64];
    const int tid = threadIdx.x;
    const int tr = tid & 15;
    const int ts = tid >> 4;
    const int s0 = blockIdx.x * 64;
    const int rt = blockIdx.y;            // r0 = rt*128
    const int wphys = tr * 8 + ((tr >> 2) << 2);

    float acc[8][4];
    #pragma unroll
    for (int x = 0; x < 8; ++x)
        #pragma unroll
        for (int y = 0; y < 4; ++y) acc[x][y] = 0.f;

    auto issue_w = [&](int c, int b) {
        const float* src = WT + (size_t)(rt * 256 + c * 32) * WROW;
        #pragma unroll
        for (int p = 0; p < 4; ++p) {
            int idx = tid + p * 256;
            gload_lds16(src + idx * 4, &w_lds[b][idx * 4]);
        }
        if (tid < 96) {
            int idx = 1024 + tid;
            gload_lds16(src + idx * 4, &w_lds[b][idx * 4]);
        }
    };
    auto issue_h = [&](int k0, int b) {
        #pragma unroll
        for (int p = 0; p < 2; ++p) {
            int idx = tid + p * 256;
            int jj = idx >> 4, s4 = idx & 15;
            gload_lds16(&X[(k0 + jj) * xstride + s0 + s4 * 4],
                        &h_lds[b][jj][s4 * 4]);
        }
    };

    issue_w(0, 0); issue_h(0, 0); __syncthreads();
    for (int c = 0; c < 8; ++c) {
        const int b = c & 1;
        if (c < 7) { issue_w(c + 1, b ^ 1); issue_h((c + 1) * 32, b ^ 1); }
        #pragma unroll 4
        for (int k = 0; k < 32; ++k) {
            float4 w0 = *(const float4*)&w_lds[b][k * WROW + wphys];
            float4 w1 = *(const float4*)&w_lds[b][k * WROW + wphys + 4];
            float4 hv = *(const float4*)&h_lds[b][k][ts * 4];
            float wa[8] = {w0.x, w0.y, w0.z, w0.w, w1.x, w1.y, w1.z, w1.w};
            float ha[4] = {hv.x, hv.y, hv.z, hv.w};
            #pragma unroll
            for (int ri = 0; ri < 8; ++ri)
                #pragma unroll
                for (int si = 0; si < 4; ++si)
                    acc[ri][si] += wa[ri] * ha[si];
        }
        __syncthreads();
    }

    const int scol = s0 + ts * 4;
    #pragma unroll
    for (int ri = 0; ri < 8; ++ri) {
        const int r = rt * 128 + tr * 8 + ri;
        float4 z;
        if (addm) {
            float4 gb = *(const float4*)&addm[r * 4096 + scol];
            z.x = acc[ri][0] + gb.x; z.y = acc[ri][1] + gb.y;
            z.z = acc[ri][2] + gb.z; z.w = acc[ri][3] + gb.w;
        } else {
            float bb = bias[r];
            z.x = acc[ri][0] + bb; z.y = acc[ri][1] + bb;
            z.z = acc[ri][2] + bb; z.w = acc[ri][3] + bb;
        }
        *(float4*)&Out[r * 4096 + scol] = z;
    }
}

// ---------------------------------------------------------------------------
// Sweep scan: exact per-unit affine scan of c given gate preactivations ZT,
// then h = sig(o)*tanh(c) -> hTbuf[u][1+s]. grid 256, block 256.
// ---------------------------------------------------------------------------
__global__ __launch_bounds__(256, 1)
void scan_sweep(const float* __restrict__ ZT, float* __restrict__ hTbuf)
{
    const int u = blockIdx.x;
    const int t = threadIdx.x;
    const int s0 = t * 16;

    const float* zi = ZT + (0 * 256 + u) * 4096 + s0;
    const float* zf = ZT + (1 * 256 + u) * 4096 + s0;
    const float* zg = ZT + (2 * 256 + u) * 4096 + s0;
    const float* zo = ZT + (3 * 256 + u) * 4096 + s0;

    float4 iv[4], fv[4], gv[4], ov[4];
    #pragma unroll
    for (int p = 0; p < 4; ++p) {
        iv[p] = *(const float4*)&zi[p * 4];
        fv[p] = *(const float4*)&zf[p * 4];
        gv[p] = *(const float4*)&zg[p * 4];
        ov[p] = *(const float4*)&zo[p * 4];
    }
    float af[16], uu[16];
    const float* ivp = (const float*)iv;
    const float* fvp = (const float*)fv;
    const float* gvp = (const float*)gv;
    float A = 1.f, U = 0.f;
    #pragma unroll
    for (int k = 0; k < 16; ++k) {
        af[k] = sig_(fvp[k]);
        uu[k] = sig_(ivp[k]) * th_(gvp[k]);
        U = af[k] * U + uu[k];
        A = af[k] * A;
    }

    __shared__ float As[256], Us[256];
    As[t] = A; Us[t] = U;
    __syncthreads();
    #pragma unroll
    for (int off = 1; off < 256; off <<= 1) {
        float eA = 1.f, eU = 0.f;
        if (t >= off) { eA = As[t - off]; eU = Us[t - off]; }
        __syncthreads();
        U = A * eU + U;
        A = A * eA;
        As[t] = A; Us[t] = U;
        __syncthreads();
    }
    float c = (t > 0) ? Us[t - 1] : 0.f;  // exclusive prefix -> entry c

    float* hp = hTbuf + u * HSTRIDE + 1 + s0;
    const float* ovp = (const float*)ov;
    #pragma unroll
    for (int k = 0; k < 16; ++k) {
        c = af[k] * c + uu[k];
        hp[k] = sig_(ovp[k]) * th_(c);
    }
}

// ---------------------------------------------------------------------------
// Final linear: out = h[4095] . lin_W + lin_b
// ---------------------------------------------------------------------------
__global__ __launch_bounds__(256)
void out_kernel(const float* __restrict__ hTbuf, const float* __restrict__ linW,
                const float* __restrict__ linb, float* __restrict__ out)
{
    const int tid = threadIdx.x;
    __shared__ float red_lds[4];
    float p = hTbuf[tid * HSTRIDE + 4096] * linW[tid];
    #pragma unroll
    for (int off = 1; off < 64; off <<= 1) p += __shfl_xor(p, off);
    if ((tid & 63) == 0) red_lds[tid >> 6] = p;
    __syncthreads();
    if (tid == 0)
        out[0] = red_lds[0] + red_lds[1] + red_lds[2] + red_lds[3] + linb[0];
}

extern "C" void kernel_launch(void* const* d_in, const int* in_sizes, int n_in,
                              void* d_out, int out_size, void* d_ws, size_t ws_size,
                              hipStream_t stream)
{
    const int*   tok  = (const int*)d_in[0];
    const int*   len  = (const int*)d_in[1];
    const float* emb  = (const float*)d_in[2];
    const float* tWih = (const float*)d_in[3];
    const float* tWhh = (const float*)d_in[4];
    const float* tb   = (const float*)d_in[5];
    const float* iWih = (const float*)d_in[6];
    const float* iWhh = (const float*)d_in[7];
    const float* ib   = (const float*)d_in[8];
    const float* lW   = (const float*)d_in[9];
    const float* lb   = (const float*)d_in[10];
    float* out = (float*)d_out;

    // workspace (floats), ~48 MB; ZT (phase 2) aliases hT0..featsT (dead)
    float* emb2   = (float*)d_ws;           // [2000][1024]   8 MB
    float* hT0    = emb2   + 2048000;       // [256][4096]    4 MB
    float* hT1    = hT0    + 1048576;       // [256][4096]
    float* cT     = hT1    + 1048576;       // [256][4096]
    float* featsT = cT     + 1048576;       // [256][4096]
    float* gBT    = featsT + 1048576;       // [1024][4096]  16 MB
    float* hTbuf  = gBT    + 4194304;       // [256][HSTRIDE], col0 = 0 pad
    float* tWhhT  = hTbuf  + 256 * HSTRIDE; // skewed W images, 1.1 MB each
    float* iWhhT  = tWhhT  + WTSZ;
    float* iWihT  = iWhhT  + WTSZ;
    int*   perm   = (int*)(iWihT + WTSZ);   // [4096]
    int*   actcnt = perm + 4096;            // [17]
    float* ZT     = hT0;                    // [1024][4096] alias (phase 2 only)

    // hTbuf col 0 must be 0 (h[-1])
    hipMemsetAsync(hTbuf, 0, (size_t)256 * HSTRIDE * sizeof(float), stream);

    // one-time pre-transposed + pre-skewed W images
    wtrans<<<dim3(8, 8), 256, 0, stream>>>(tWhh, tWhhT, 1);   // gate-interleaved
    wtrans<<<dim3(8, 8), 256, 0, stream>>>(iWhh, iWhhT, 0);   // linear
    wtrans<<<dim3(8, 8), 256, 0, stream>>>(iWih, iWihT, 0);   // linear

    // ---- phase 1: token LSTM, transposed, length-sorted batch-parallel ----
    sortlen<<<1, 256, 0, stream>>>(len, perm, actcnt);
    gemm_emb2<<<dim3(32, 16), 256, 0, stream>>>(emb, tWih, tb, emb2, 2000);
    step0T<<<dim3(64, 16), 256, 0, stream>>>(tok, perm, actcnt, emb2, cT, hT0,
                                             featsT);
    for (int t = 1; t < 16; ++t) {
        float* hprev = (t & 1) ? hT0 : hT1;
        float* hcur  = (t & 1) ? hT1 : hT0;
        stepT<<<dim3(64, 8), 256, 0, stream>>>(tWhhT, hprev, tok, t, emb2, perm,
                                               actcnt, cT, hcur, featsT);
    }
    // gBT[r][s] = ins_W_ih . featsT + ins_b
    gemm_T<<<dim3(64, 8), 256, 0, stream>>>(iWihT, featsT, 4096, nullptr, ib, gBT);

    // ---- phase 2: fixed-point sweeps (no cross-block sync) ----
    scan_sweep<<<256, 256, 0, stream>>>(gBT, hTbuf);    // sweep 1: h_old = 0
    for (int k = 1; k < SWEEPS; ++k) {
        gemm_T<<<dim3(64, 8), 256, 0, stream>>>(iWhhT, hTbuf, HSTRIDE, gBT,
                                                nullptr, ZT);
        scan_sweep<<<256, 256, 0, stream>>>(ZT, hTbuf);
    }

    out_kernel<<<1, 256, 0, stream>>>(hTbuf, lW, lb, out);
}